// Round 3
// baseline (637.537 us; speedup 1.0000x reference)
//
#include <hip/hip_runtime.h>
#include <hip/hip_bf16.h>
#include <stdint.h>

#define B_ 4
#define S_ 2048
#define D_ 1024
#define H_ 16
#define DK_ 64

typedef __hip_bfloat16 bf16;
typedef __attribute__((ext_vector_type(8))) __bf16 bf16x8;
typedef __attribute__((ext_vector_type(4))) __bf16 bf16x4;
typedef __attribute__((ext_vector_type(4))) float f32x4;

__device__ __forceinline__ void async_copy16(const void* g, void* l) {
    __builtin_amdgcn_global_load_lds((const __attribute__((address_space(1))) void*)g,
                                     (__attribute__((address_space(3))) void*)l,
                                     16, 0, 0);
}

__device__ __forceinline__ bf16x8 ld8(const bf16* p) {
    return *(const bf16x8*)p;
}

// f32 -> bf16 conversion, 4 elems/thread
__global__ __launch_bounds__(256) void cvt_f32_bf16(const float4* __restrict__ src,
                                                    bf16x4* __restrict__ dst, int n4) {
    int i = blockIdx.x * 256 + threadIdx.x;
    if (i < n4) {
        float4 f = src[i];
        bf16x4 o = {(__bf16)f.x, (__bf16)f.y, (__bf16)f.z, (__bf16)f.w};
        dst[i] = o;
    }
}

// C[m,n] = sum_k A[m,k] * W[n,k]  (A: [M x 1024] bf16 K-major, W: [1024 x 1024] bf16 K-major)
// mode 0: bf16 out[((b*H+h)*S + s)*DK + dk]   (Q/K proj)
// mode 1: bf16 out[((b*H+h)*DK + dk)*S + s]   (V proj, transposed for PV B-fragments)
// mode 2: f32  out[m*1024 + n]                (final projection -> d_out, float32)
__global__ __launch_bounds__(256) void gemm_bt(const bf16* __restrict__ A,
                                               const bf16* __restrict__ W,
                                               void* __restrict__ out,
                                               int mode) {
    __shared__ bf16 lA[128 * 32];
    __shared__ bf16 lW[128 * 32];
    const int tid  = threadIdx.x;
    const int lane = tid & 63;
    const int quad = lane >> 4;
    const int lo   = lane & 15;
    const int wave = tid >> 6;
    const int wm   = (wave >> 1) * 64;
    const int wn   = (wave & 1) * 64;
    const int n0   = blockIdx.x * 128;
    const int m0   = blockIdx.y * 128;
    const int K    = 1024;

    f32x4 acc[4][4];
#pragma unroll
    for (int i = 0; i < 4; i++)
#pragma unroll
        for (int j = 0; j < 4; j++) acc[i][j] = (f32x4){0.f, 0.f, 0.f, 0.f};

    const int sr = tid >> 2;        // 0..63
    const int sc = (tid & 3) * 8;   // 0,8,16,24

    for (int k0 = 0; k0 < K; k0 += 32) {
        // stage A[128x32], W[128x32] into LDS (16B per lane, lane-contiguous)
        async_copy16(A + (size_t)(m0 + sr) * K + k0 + sc,       lA + sr * 32 + sc);
        async_copy16(A + (size_t)(m0 + 64 + sr) * K + k0 + sc,  lA + (64 + sr) * 32 + sc);
        async_copy16(W + (size_t)(n0 + sr) * K + k0 + sc,       lW + sr * 32 + sc);
        async_copy16(W + (size_t)(n0 + 64 + sr) * K + k0 + sc,  lW + (64 + sr) * 32 + sc);
        __syncthreads();   // drains vmcnt -> LDS populated

        bf16x8 af[4], bfr[4];
#pragma unroll
        for (int i = 0; i < 4; i++)
            af[i] = ld8(lA + (wm + i * 16 + lo) * 32 + quad * 8);
#pragma unroll
        for (int j = 0; j < 4; j++)
            bfr[j] = ld8(lW + (wn + j * 16 + lo) * 32 + quad * 8);
#pragma unroll
        for (int i = 0; i < 4; i++)
#pragma unroll
            for (int j = 0; j < 4; j++)
                acc[i][j] = __builtin_amdgcn_mfma_f32_16x16x32_bf16(af[i], bfr[j], acc[i][j], 0, 0, 0);
        __syncthreads();   // everyone done reading before next overwrite
    }

#pragma unroll
    for (int i = 0; i < 4; i++)
#pragma unroll
        for (int j = 0; j < 4; j++)
#pragma unroll
            for (int r = 0; r < 4; r++) {
                int m = m0 + wm + i * 16 + quad * 4 + r;
                int n = n0 + wn + j * 16 + lo;
                if (mode == 0) {
                    int b = m >> 11, s = m & (S_ - 1);
                    int h = n >> 6, dk = n & 63;
                    ((bf16*)out)[((size_t)(b * H_ + h) * S_ + s) * DK_ + dk] =
                        __float2bfloat16(acc[i][j][r]);
                } else if (mode == 1) {
                    int b = m >> 11, s = m & (S_ - 1);
                    int h = n >> 6, dk = n & 63;
                    ((bf16*)out)[((size_t)(b * H_ + h) * DK_ + dk) * S_ + s] =
                        __float2bfloat16(acc[i][j][r]);
                } else {
                    ((float*)out)[(size_t)m * D_ + n] = acc[i][j][r];
                }
            }
}

// Flash attention, causal. 1 wave per block, 16 q rows.
// Q,K: [B*H, S, DK] bf16; Vt: [B*H, DK, S] bf16; X out: [B, S, D] bf16 (d = h*64+dk)
__global__ __launch_bounds__(64) void attn(const bf16* __restrict__ Q,
                                           const bf16* __restrict__ K,
                                           const bf16* __restrict__ Vt,
                                           bf16* __restrict__ X) {
    __shared__ bf16 lP[16 * 32];
    const int lane = threadIdx.x;
    const int quad = lane >> 4;
    const int lo   = lane & 15;
    const int qb   = blockIdx.x;   // 0..127
    const int bh   = blockIdx.y;   // 0..63
    const int q0   = qb * 16;

    const bf16* Qp = Q  + (size_t)bh * S_ * DK_;
    const bf16* Kp = K  + (size_t)bh * S_ * DK_;
    const bf16* Vp = Vt + (size_t)bh * DK_ * S_;

    bf16x8 aQ0 = ld8(Qp + (size_t)(q0 + lo) * DK_ + quad * 8);
    bf16x8 aQ1 = ld8(Qp + (size_t)(q0 + lo) * DK_ + 32 + quad * 8);

    float m_run[4], l_run[4];
    f32x4 acc[4];
#pragma unroll
    for (int r = 0; r < 4; r++) { m_run[r] = -1e30f; l_run[r] = 0.f; }
#pragma unroll
    for (int t = 0; t < 4; t++) acc[t] = (f32x4){0.f, 0.f, 0.f, 0.f};

    const float c = 1.44269504f;
    const int kv_end = q0 + 16;   // exclusive col bound for this q block

    for (int kv0 = 0; kv0 < kv_end; kv0 += 32) {
        // S = Q K^T for a 16x32 score tile (two 16x16 MFMA n-tiles, 2 k-steps over DK)
        f32x4 sc[2];
        sc[0] = (f32x4){0.f, 0.f, 0.f, 0.f};
        sc[1] = (f32x4){0.f, 0.f, 0.f, 0.f};
#pragma unroll
        for (int t = 0; t < 2; t++) {
            bf16x8 bK0 = ld8(Kp + (size_t)(kv0 + t * 16 + lo) * DK_ + quad * 8);
            bf16x8 bK1 = ld8(Kp + (size_t)(kv0 + t * 16 + lo) * DK_ + 32 + quad * 8);
            sc[t] = __builtin_amdgcn_mfma_f32_16x16x32_bf16(aQ0, bK0, sc[t], 0, 0, 0);
            sc[t] = __builtin_amdgcn_mfma_f32_16x16x32_bf16(aQ1, bK1, sc[t], 0, 0, 0);
        }

        // mask + online softmax (C-layout: row = quad*4+r, col = lane&15)
#pragma unroll
        for (int r = 0; r < 4; r++) {
            int row = q0 + quad * 4 + r;
            float s0 = (kv0 + lo      <= row) ? sc[0][r] * 0.125f : -1e30f;
            float s1 = (kv0 + 16 + lo <= row) ? sc[1][r] * 0.125f : -1e30f;
            float mv = fmaxf(s0, s1);
            mv = fmaxf(mv, __shfl_xor(mv, 1));
            mv = fmaxf(mv, __shfl_xor(mv, 2));
            mv = fmaxf(mv, __shfl_xor(mv, 4));
            mv = fmaxf(mv, __shfl_xor(mv, 8));
            float mnew  = fmaxf(m_run[r], mv);
            float alpha = exp2f((m_run[r] - mnew) * c);
            float p0 = exp2f((s0 - mnew) * c);
            float p1 = exp2f((s1 - mnew) * c);
            float ps = p0 + p1;
            ps += __shfl_xor(ps, 1);
            ps += __shfl_xor(ps, 2);
            ps += __shfl_xor(ps, 4);
            ps += __shfl_xor(ps, 8);
            l_run[r] = l_run[r] * alpha + ps;
            m_run[r] = mnew;
            lP[(quad * 4 + r) * 32 + lo]      = __float2bfloat16(p0);
            lP[(quad * 4 + r) * 32 + 16 + lo] = __float2bfloat16(p1);
#pragma unroll
            for (int t = 0; t < 4; t++) acc[t][r] *= alpha;
        }
        __syncthreads();   // lP writes visible
        bf16x8 pa = ld8(lP + lo * 32 + quad * 8);   // P in A-layout
#pragma unroll
        for (int t = 0; t < 4; t++) {
            bf16x8 bV = ld8(Vp + (size_t)(t * 16 + lo) * S_ + kv0 + quad * 8);
            acc[t] = __builtin_amdgcn_mfma_f32_16x16x32_bf16(pa, bV, acc[t], 0, 0, 0);
        }
        __syncthreads();   // lP reads done before next overwrite
    }

    const int b = bh >> 4, h = bh & 15;
#pragma unroll
    for (int t = 0; t < 4; t++)
#pragma unroll
        for (int r = 0; r < 4; r++) {
            int q = q0 + quad * 4 + r;
            int d = h * 64 + t * 16 + lo;
            X[(size_t)(b * S_ + q) * D_ + d] = __float2bfloat16(acc[t][r] / l_run[r]);
        }
}

extern "C" void kernel_launch(void* const* d_in, const int* in_sizes, int n_in,
                              void* d_out, int out_size, void* d_ws, size_t ws_size,
                              hipStream_t stream) {
    // Reference dtypes: q,k,v,w_* are float32; mask int32 (ignored: exact tril).
    const float* q  = (const float*)d_in[0];
    const float* k  = (const float*)d_in[1];
    const float* v  = (const float*)d_in[2];
    const float* wq = (const float*)d_in[4];
    const float* wk = (const float*)d_in[5];
    const float* wv = (const float*)d_in[6];
    const float* wo = (const float*)d_in[7];

    const size_t elems = (size_t)B_ * S_ * D_;   // 8388608
    const size_t welems = (size_t)D_ * D_;       // 1048576
    // ws layout (bf16): tmp[elems] | wb[welems] | Qw[elems] | Kw[elems] | Vw[elems]
    // total = (4*8388608 + 1048576) * 2B = 69.2 MB
    bf16* tmp = (bf16*)d_ws;
    bf16* wb  = tmp + elems;
    bf16* Qw  = wb + welems;
    bf16* Kw  = Qw + elems;
    bf16* Vw  = Kw + elems;

    const int n4a = (int)(elems / 4);     // 2097152 -> 8192 blocks
    const int n4w = (int)(welems / 4);    // 262144  -> 1024 blocks
    dim3 gg(D_ / 128, (B_ * S_) / 128);   // (8, 64)

    // Q projection
    hipLaunchKernelGGL(cvt_f32_bf16, dim3(n4a / 256), dim3(256), 0, stream,
                       (const float4*)q, (bf16x4*)tmp, n4a);
    hipLaunchKernelGGL(cvt_f32_bf16, dim3(n4w / 256), dim3(256), 0, stream,
                       (const float4*)wq, (bf16x4*)wb, n4w);
    hipLaunchKernelGGL(gemm_bt, gg, dim3(256), 0, stream, tmp, wb, (void*)Qw, 0);
    // K projection
    hipLaunchKernelGGL(cvt_f32_bf16, dim3(n4a / 256), dim3(256), 0, stream,
                       (const float4*)k, (bf16x4*)tmp, n4a);
    hipLaunchKernelGGL(cvt_f32_bf16, dim3(n4w / 256), dim3(256), 0, stream,
                       (const float4*)wk, (bf16x4*)wb, n4w);
    hipLaunchKernelGGL(gemm_bt, gg, dim3(256), 0, stream, tmp, wb, (void*)Kw, 0);
    // V projection (transposed output)
    hipLaunchKernelGGL(cvt_f32_bf16, dim3(n4a / 256), dim3(256), 0, stream,
                       (const float4*)v, (bf16x4*)tmp, n4a);
    hipLaunchKernelGGL(cvt_f32_bf16, dim3(n4w / 256), dim3(256), 0, stream,
                       (const float4*)wv, (bf16x4*)wb, n4w);
    hipLaunchKernelGGL(gemm_bt, gg, dim3(256), 0, stream, tmp, wb, (void*)Vw, 1);
    // attention -> X (bf16) into tmp (free now)
    hipLaunchKernelGGL(attn, dim3(S_ / 16, B_ * H_), dim3(64), 0, stream, Qw, Kw, Vw, tmp);
    // output projection -> d_out (float32)
    hipLaunchKernelGGL(cvt_f32_bf16, dim3(n4w / 256), dim3(256), 0, stream,
                       (const float4*)wo, (bf16x4*)wb, n4w);
    hipLaunchKernelGGL(gemm_bt, gg, dim3(256), 0, stream, tmp, wb, d_out, 2);
}

// Round 4
// 545.988 us; speedup vs baseline: 1.1677x; 1.1677x over previous
//
#include <hip/hip_runtime.h>
#include <hip/hip_bf16.h>
#include <stdint.h>

#define B_ 4
#define S_ 2048
#define D_ 1024
#define H_ 16
#define DK_ 64

typedef __hip_bfloat16 bf16;
typedef __attribute__((ext_vector_type(8))) __bf16 bf16x8;
typedef __attribute__((ext_vector_type(4))) __bf16 bf16x4;
typedef __attribute__((ext_vector_type(4))) float f32x4;
typedef __attribute__((ext_vector_type(4))) uint32_t u32x4;

// scale 1/sqrt(DK) folded with log2(e): Q is pre-scaled so p = exp2(S^T) directly
#define QSCALE 0.18033688011112042f   // 0.125 * 1.4426950408889634

__device__ __forceinline__ void async_copy16(const void* g, void* l) {
    __builtin_amdgcn_global_load_lds((const __attribute__((address_space(1))) void*)g,
                                     (__attribute__((address_space(3))) void*)l,
                                     16, 0, 0);
}

__device__ __forceinline__ bf16x8 ld8(const bf16* p) {
    return *(const bf16x8*)p;
}

// pack two f32 -> one dword of 2 bf16 (RNE)
__device__ __forceinline__ uint32_t pk2(float a, float b) {
    union { __bf16 h; uint16_t u; } x, y;
    x.h = (__bf16)a; y.h = (__bf16)b;
    return (uint32_t)x.u | ((uint32_t)y.u << 16);
}

// fused f32->bf16 convert: activation buffer + weight buffer in one launch
__global__ __launch_bounds__(256) void cvt2(const float4* __restrict__ sA,
                                            bf16x4* __restrict__ dA, int n4a,
                                            const float4* __restrict__ sW,
                                            bf16x4* __restrict__ dW, int n4w) {
    int i = blockIdx.x * 256 + threadIdx.x;
    if (i < n4a) {
        float4 f = sA[i];
        dA[i] = (bf16x4){(__bf16)f.x, (__bf16)f.y, (__bf16)f.z, (__bf16)f.w};
    } else {
        int j = i - n4a;
        if (j < n4w) {
            float4 f = sW[j];
            dW[j] = (bf16x4){(__bf16)f.x, (__bf16)f.y, (__bf16)f.z, (__bf16)f.w};
        }
    }
}

// C[m,n] = sum_k A[m,k] * W[n,k]
// mode 0: bf16 out[((b*H+h)*S + s)*DK + dk]       (K proj)
// mode 3: same as 0 but acc *= QSCALE              (Q proj, scale folded)
// mode 1: bf16 out[((b*H+h)*DK + dk)*S + s]        (V proj, transposed)
// mode 2: f32  out[m*1024 + n]                     (final projection -> d_out)
__global__ __launch_bounds__(256) void gemm_bt(const bf16* __restrict__ A,
                                               const bf16* __restrict__ W,
                                               void* __restrict__ out,
                                               int mode) {
    __shared__ bf16 lA[128 * 32];
    __shared__ bf16 lW[128 * 32];
    const int tid  = threadIdx.x;
    const int lane = tid & 63;
    const int quad = lane >> 4;
    const int lo   = lane & 15;
    const int wave = tid >> 6;
    const int wm   = (wave >> 1) * 64;
    const int wn   = (wave & 1) * 64;
    const int n0   = blockIdx.x * 128;
    const int m0   = blockIdx.y * 128;
    const int K    = 1024;

    f32x4 acc[4][4];
#pragma unroll
    for (int i = 0; i < 4; i++)
#pragma unroll
        for (int j = 0; j < 4; j++) acc[i][j] = (f32x4){0.f, 0.f, 0.f, 0.f};

    const int sr = tid >> 2;
    const int sc = (tid & 3) * 8;

    for (int k0 = 0; k0 < K; k0 += 32) {
        async_copy16(A + (size_t)(m0 + sr) * K + k0 + sc,       lA + sr * 32 + sc);
        async_copy16(A + (size_t)(m0 + 64 + sr) * K + k0 + sc,  lA + (64 + sr) * 32 + sc);
        async_copy16(W + (size_t)(n0 + sr) * K + k0 + sc,       lW + sr * 32 + sc);
        async_copy16(W + (size_t)(n0 + 64 + sr) * K + k0 + sc,  lW + (64 + sr) * 32 + sc);
        __syncthreads();

        bf16x8 af[4], bfr[4];
#pragma unroll
        for (int i = 0; i < 4; i++)
            af[i] = ld8(lA + (wm + i * 16 + lo) * 32 + quad * 8);
#pragma unroll
        for (int j = 0; j < 4; j++)
            bfr[j] = ld8(lW + (wn + j * 16 + lo) * 32 + quad * 8);
#pragma unroll
        for (int i = 0; i < 4; i++)
#pragma unroll
            for (int j = 0; j < 4; j++)
                acc[i][j] = __builtin_amdgcn_mfma_f32_16x16x32_bf16(af[i], bfr[j], acc[i][j], 0, 0, 0);
        __syncthreads();
    }

#pragma unroll
    for (int i = 0; i < 4; i++)
#pragma unroll
        for (int j = 0; j < 4; j++)
#pragma unroll
            for (int r = 0; r < 4; r++) {
                int m = m0 + wm + i * 16 + quad * 4 + r;
                int n = n0 + wn + j * 16 + lo;
                float val = acc[i][j][r];
                if (mode == 3) val *= QSCALE;
                if (mode == 0 || mode == 3) {
                    int b = m >> 11, s = m & (S_ - 1);
                    int h = n >> 6, dk = n & 63;
                    ((bf16*)out)[((size_t)(b * H_ + h) * S_ + s) * DK_ + dk] = __float2bfloat16(val);
                } else if (mode == 1) {
                    int b = m >> 11, s = m & (S_ - 1);
                    int h = n >> 6, dk = n & 63;
                    ((bf16*)out)[((size_t)(b * H_ + h) * DK_ + dk) * S_ + s] = __float2bfloat16(val);
                } else {
                    ((float*)out)[(size_t)m * D_ + n] = val;
                }
            }
}

// Transposed flash attention, causal, no-max softmax. 1 wave / 16 q rows.
// Q (pre-scaled by QSCALE), K: [B*H, S, DK]; Vt: [B*H, DK, S]; X: [B, S, D]
// S^T = K Q^T : C-layout col = q (lane&15), row = kv (quad*4+r)  -> rowsum per-lane!
// O^T = Vt P^T: C-layout col = q, row = dk -> 4 consecutive d per lane.
__global__ __launch_bounds__(64) void attn(const bf16* __restrict__ Q,
                                           const bf16* __restrict__ K,
                                           const bf16* __restrict__ Vt,
                                           bf16* __restrict__ X) {
    const int lane = threadIdx.x;
    const int quad = lane >> 4;
    const int lo   = lane & 15;
    // XCD swizzle: bh = idx & 63 -> all q-blocks of a head on one XCD (bh%8)
    const int idx  = blockIdx.x;
    const int bh   = idx & 63;
    const int qb   = idx >> 6;     // 0..127
    const int q0   = qb * 16;

    const bf16* Qp = Q  + (size_t)bh * S_ * DK_;
    const bf16* Kp = K  + (size_t)bh * S_ * DK_;
    const bf16* Vp = Vt + (size_t)bh * DK_ * S_;

    // Q B-fragments: B[k=dk][n=q]: lane needs Q[q0+lo][quad*8+j]
    bf16x8 bQ0 = ld8(Qp + (size_t)(q0 + lo) * DK_ + quad * 8);
    bf16x8 bQ1 = ld8(Qp + (size_t)(q0 + lo) * DK_ + 32 + quad * 8);

    f32x4 out[4];
#pragma unroll
    for (int t = 0; t < 4; t++) out[t] = (f32x4){0.f, 0.f, 0.f, 0.f};
    float lsum = 0.f;

    const int nfull = q0 >> 5;           // unmasked 32-wide iterations
    const int srcl  = ((quad & 1) * 2) * 16 + lo;   // bpermute source lanes
    const bool loT  = (quad < 2);

    for (int it = 0; it <= nfull; ++it) {
        const int kv0 = it * 32;
        const bool masked = (it == nfull);

        // S^T tiles: A=K rows (m=kv), B=Q (n=q)
        const bf16* k0p = Kp + (size_t)(kv0 + lo) * DK_ + quad * 8;
        bf16x8 a00 = ld8(k0p), a01 = ld8(k0p + 32);
        bf16x8 a10 = ld8(k0p + 16 * DK_), a11 = ld8(k0p + 16 * DK_ + 32);
        f32x4 st0 = (f32x4){0.f, 0.f, 0.f, 0.f};
        f32x4 st1 = (f32x4){0.f, 0.f, 0.f, 0.f};
        st0 = __builtin_amdgcn_mfma_f32_16x16x32_bf16(a00, bQ0, st0, 0, 0, 0);
        st0 = __builtin_amdgcn_mfma_f32_16x16x32_bf16(a01, bQ1, st0, 0, 0, 0);
        st1 = __builtin_amdgcn_mfma_f32_16x16x32_bf16(a10, bQ0, st1, 0, 0, 0);
        st1 = __builtin_amdgcn_mfma_f32_16x16x32_bf16(a11, bQ1, st1, 0, 0, 0);

        // p = exp2(s); masked entries -> 0; per-lane rowsum (col q = lo fixed)
        float p0[4], p1[4];
#pragma unroll
        for (int r = 0; r < 4; r++) {
            float e0 = exp2f(st0[r]);
            float e1 = exp2f(st1[r]);
            if (masked) {
                e0 = (kv0 + quad * 4 + r <= q0 + lo) ? e0 : 0.f;
                e1 = (kv0 + 16 + quad * 4 + r <= q0 + lo) ? e1 : 0.f;
            }
            p0[r] = e0; p1[r] = e1;
            lsum += e0 + e1;
        }

        // build P^T B-frag (k=kv0..kv0+31, n=q) from C-layout via bpermute
        uint32_t pkA0 = pk2(p0[0], p0[1]), pkA1 = pk2(p0[2], p0[3]);
        uint32_t pkB0 = pk2(p1[0], p1[1]), pkB1 = pk2(p1[2], p1[3]);
        u32x4 dw;
#pragma unroll
        for (int i = 0; i < 4; i++) {
            int sl = srcl + (i >> 1) * 16;
            uint32_t vA = (uint32_t)__shfl((int)((i & 1) ? pkA1 : pkA0), sl, 64);
            uint32_t vB = (uint32_t)__shfl((int)((i & 1) ? pkB1 : pkB0), sl, 64);
            dw[i] = loT ? vA : vB;
        }
        bf16x8 bP = __builtin_bit_cast(bf16x8, dw);

        // O^T += Vt P^T : A = Vt rows (m=dk), B = P^T (n=q)
#pragma unroll
        for (int t = 0; t < 4; t++) {
            bf16x8 aV = ld8(Vp + (size_t)(t * 16 + lo) * S_ + kv0 + quad * 8);
            out[t] = __builtin_amdgcn_mfma_f32_16x16x32_bf16(aV, bP, out[t], 0, 0, 0);
        }
    }

    // finish rowsum across the 4 quads holding the same q
    lsum += __shfl_xor(lsum, 16, 64);
    lsum += __shfl_xor(lsum, 32, 64);
    float rl = 1.f / lsum;

    // write: lane holds col q = lo, rows dk = t*16 + quad*4 + r (consecutive r)
    const int b = bh >> 4, h = bh & 15;
    bf16* Xp = X + (size_t)(b * S_ + q0 + lo) * D_ + h * 64;
#pragma unroll
    for (int t = 0; t < 4; t++) {
        uint32_t o0 = pk2(out[t][0] * rl, out[t][1] * rl);
        uint32_t o1 = pk2(out[t][2] * rl, out[t][3] * rl);
        uint32_t* dst = (uint32_t*)(Xp + t * 16 + quad * 4);
        dst[0] = o0;
        dst[1] = o1;
    }
}

extern "C" void kernel_launch(void* const* d_in, const int* in_sizes, int n_in,
                              void* d_out, int out_size, void* d_ws, size_t ws_size,
                              hipStream_t stream) {
    const float* q  = (const float*)d_in[0];
    const float* k  = (const float*)d_in[1];
    const float* v  = (const float*)d_in[2];
    const float* wq = (const float*)d_in[4];
    const float* wk = (const float*)d_in[5];
    const float* wv = (const float*)d_in[6];
    const float* wo = (const float*)d_in[7];

    const size_t elems = (size_t)B_ * S_ * D_;   // 8388608
    const size_t welems = (size_t)D_ * D_;       // 1048576
    // ws (bf16): Xb[elems] | Wb[welems] | Qw | Kw | Vw  = 69.2 MB (proven fit)
    bf16* Xb = (bf16*)d_ws;
    bf16* Wb = Xb + elems;
    bf16* Qw = Wb + welems;
    bf16* Kw = Qw + elems;
    bf16* Vw = Kw + elems;

    const int n4a = (int)(elems / 4);     // 2097152
    const int n4w = (int)(welems / 4);    // 262144
    const int cg  = (n4a + n4w) / 256;    // 9216 blocks
    dim3 gg(D_ / 128, (B_ * S_) / 128);   // (8, 64)

    hipLaunchKernelGGL(cvt2, dim3(cg), dim3(256), 0, stream,
                       (const float4*)q, (bf16x4*)Xb, n4a, (const float4*)wq, (bf16x4*)Wb, n4w);
    hipLaunchKernelGGL(gemm_bt, gg, dim3(256), 0, stream, Xb, Wb, (void*)Qw, 3);
    hipLaunchKernelGGL(cvt2, dim3(cg), dim3(256), 0, stream,
                       (const float4*)k, (bf16x4*)Xb, n4a, (const float4*)wk, (bf16x4*)Wb, n4w);
    hipLaunchKernelGGL(gemm_bt, gg, dim3(256), 0, stream, Xb, Wb, (void*)Kw, 0);
    hipLaunchKernelGGL(cvt2, dim3(cg), dim3(256), 0, stream,
                       (const float4*)v, (bf16x4*)Xb, n4a, (const float4*)wv, (bf16x4*)Wb, n4w);
    hipLaunchKernelGGL(gemm_bt, gg, dim3(256), 0, stream, Xb, Wb, (void*)Vw, 1);

    hipLaunchKernelGGL(attn, dim3((S_ / 16) * B_ * H_), dim3(64), 0, stream, Qw, Kw, Vw, Xb);

    hipLaunchKernelGGL(cvt2, dim3(n4w / 256), dim3(256), 0, stream,
                       (const float4*)nullptr, (bf16x4*)nullptr, 0,
                       (const float4*)wo, (bf16x4*)Wb, n4w);
    hipLaunchKernelGGL(gemm_bt, gg, dim3(256), 0, stream, Xb, Wb, d_out, 2);
}

// Round 5
// 433.490 us; speedup vs baseline: 1.4707x; 1.2595x over previous
//
#include <hip/hip_runtime.h>
#include <hip/hip_bf16.h>
#include <stdint.h>

#define B_ 4
#define S_ 2048
#define D_ 1024
#define H_ 16
#define DK_ 64

typedef __hip_bfloat16 bf16;
typedef __attribute__((ext_vector_type(8))) __bf16 bf16x8;
typedef __attribute__((ext_vector_type(4))) __bf16 bf16x4;
typedef __attribute__((ext_vector_type(4))) float f32x4;
typedef __attribute__((ext_vector_type(4))) uint32_t u32x4;

// scale 1/sqrt(DK) folded with log2(e): Q pre-scaled so p = exp2(S^T) directly
#define QSCALE 0.18033688011112042f   // 0.125 * 1.4426950408889634

__device__ __forceinline__ void async_copy16(const void* g, void* l) {
    __builtin_amdgcn_global_load_lds((const __attribute__((address_space(1))) void*)g,
                                     (__attribute__((address_space(3))) void*)l,
                                     16, 0, 0);
}

__device__ __forceinline__ bf16x8 ld8(const bf16* p) {
    return *(const bf16x8*)p;
}

__device__ __forceinline__ uint32_t pk2(float a, float b) {
    union { __bf16 h; uint16_t u; } x, y;
    x.h = (__bf16)a; y.h = (__bf16)b;
    return (uint32_t)x.u | ((uint32_t)y.u << 16);
}

// C-layout 16x32 P-tile (two 16x16 subtiles p0,p1) -> B-fragment of P^T (k=32, n=16)
// srcl/loT precomputed per lane. Verified end-to-end in round 4.
__device__ __forceinline__ bf16x8 transpose_p(const float* p0, const float* p1,
                                              int srcl, bool loT) {
    uint32_t x0 = pk2(p0[0], p0[1]), x1 = pk2(p0[2], p0[3]);
    uint32_t y0 = pk2(p1[0], p1[1]), y1 = pk2(p1[2], p1[3]);
    u32x4 dw;
#pragma unroll
    for (int i = 0; i < 4; i++) {
        int sl = srcl + (i >> 1) * 16;
        uint32_t vA = (uint32_t)__shfl((int)((i & 1) ? x1 : x0), sl, 64);
        uint32_t vB = (uint32_t)__shfl((int)((i & 1) ? y1 : y0), sl, 64);
        dw[i] = loT ? vA : vB;
    }
    return __builtin_bit_cast(bf16x8, dw);
}

// fused f32->bf16 convert: activation buffer + weight buffer in one launch
__global__ __launch_bounds__(256) void cvt2(const float4* __restrict__ sA,
                                            bf16x4* __restrict__ dA, int n4a,
                                            const float4* __restrict__ sW,
                                            bf16x4* __restrict__ dW, int n4w) {
    int i = blockIdx.x * 256 + threadIdx.x;
    if (i < n4a) {
        float4 f = sA[i];
        dA[i] = (bf16x4){(__bf16)f.x, (__bf16)f.y, (__bf16)f.z, (__bf16)f.w};
    } else {
        int j = i - n4a;
        if (j < n4w) {
            float4 f = sW[j];
            dW[j] = (bf16x4){(__bf16)f.x, (__bf16)f.y, (__bf16)f.z, (__bf16)f.w};
        }
    }
}

// C[m,n] = sum_k A[m,k] * W[n,k]
// mode 0: bf16 out[((b*H+h)*S + s)*DK + dk]   (K proj)
// mode 3: mode 0 with acc *= QSCALE           (Q proj)
// mode 1: bf16 out[((b*H+h)*DK + dk)*S + s]   (V proj, transposed)
// mode 2: f32  out[m*1024 + n]                (final projection -> d_out)
__global__ __launch_bounds__(256) void gemm_bt(const bf16* __restrict__ A,
                                               const bf16* __restrict__ W,
                                               void* __restrict__ out,
                                               int mode) {
    __shared__ bf16 lA[128 * 32];
    __shared__ bf16 lW[128 * 32];
    const int tid  = threadIdx.x;
    const int lane = tid & 63;
    const int quad = lane >> 4;
    const int lo   = lane & 15;
    const int wave = tid >> 6;
    const int wm   = (wave >> 1) * 64;
    const int wn   = (wave & 1) * 64;
    const int n0   = blockIdx.x * 128;
    const int m0   = blockIdx.y * 128;
    const int K    = 1024;

    f32x4 acc[4][4];
#pragma unroll
    for (int i = 0; i < 4; i++)
#pragma unroll
        for (int j = 0; j < 4; j++) acc[i][j] = (f32x4){0.f, 0.f, 0.f, 0.f};

    const int sr = tid >> 2;
    const int sc = (tid & 3) * 8;

    for (int k0 = 0; k0 < K; k0 += 32) {
        async_copy16(A + (size_t)(m0 + sr) * K + k0 + sc,       lA + sr * 32 + sc);
        async_copy16(A + (size_t)(m0 + 64 + sr) * K + k0 + sc,  lA + (64 + sr) * 32 + sc);
        async_copy16(W + (size_t)(n0 + sr) * K + k0 + sc,       lW + sr * 32 + sc);
        async_copy16(W + (size_t)(n0 + 64 + sr) * K + k0 + sc,  lW + (64 + sr) * 32 + sc);
        __syncthreads();

        bf16x8 af[4], bfr[4];
#pragma unroll
        for (int i = 0; i < 4; i++)
            af[i] = ld8(lA + (wm + i * 16 + lo) * 32 + quad * 8);
#pragma unroll
        for (int j = 0; j < 4; j++)
            bfr[j] = ld8(lW + (wn + j * 16 + lo) * 32 + quad * 8);
#pragma unroll
        for (int i = 0; i < 4; i++)
#pragma unroll
            for (int j = 0; j < 4; j++)
                acc[i][j] = __builtin_amdgcn_mfma_f32_16x16x32_bf16(af[i], bfr[j], acc[i][j], 0, 0, 0);
        __syncthreads();
    }

#pragma unroll
    for (int i = 0; i < 4; i++)
#pragma unroll
        for (int j = 0; j < 4; j++)
#pragma unroll
            for (int r = 0; r < 4; r++) {
                int m = m0 + wm + i * 16 + quad * 4 + r;
                int n = n0 + wn + j * 16 + lo;
                float val = acc[i][j][r];
                if (mode == 3) val *= QSCALE;
                if (mode == 0 || mode == 3) {
                    int b = m >> 11, s = m & (S_ - 1);
                    int h = n >> 6, dk = n & 63;
                    ((bf16*)out)[((size_t)(b * H_ + h) * S_ + s) * DK_ + dk] = __float2bfloat16(val);
                } else if (mode == 1) {
                    int b = m >> 11, s = m & (S_ - 1);
                    int h = n >> 6, dk = n & 63;
                    ((bf16*)out)[((size_t)(b * H_ + h) * DK_ + dk) * S_ + s] = __float2bfloat16(val);
                } else {
                    ((float*)out)[(size_t)m * D_ + n] = val;
                }
            }
}

// Transposed flash attention, causal, no-max softmax. 1 wave / 32 q rows (2 q-tiles).
// Q (pre-scaled), K: [B*H, S, DK]; Vt: [B*H, DK, S]; X: [B, S, D]
// S^T = K Q^T : C-layout col = q, row = kv -> per-lane rowsums, no cross-lane softmax.
__global__ __launch_bounds__(64) void attn(const bf16* __restrict__ Q,
                                           const bf16* __restrict__ K,
                                           const bf16* __restrict__ Vt,
                                           bf16* __restrict__ X) {
    const int lane = threadIdx.x;
    const int quad = lane >> 4;
    const int lo   = lane & 15;
    const int idx  = blockIdx.x;
    const int bh   = idx & 63;          // XCD locality: one head stays on one XCD
    const int qb   = 63 - (idx >> 6);   // LPT: longest q-blocks dispatched first
    const int q0   = qb * 32;

    const bf16* Qp = Q  + (size_t)bh * S_ * DK_;
    const bf16* Kp = K  + (size_t)bh * S_ * DK_;
    const bf16* Vp = Vt + (size_t)bh * DK_ * S_;

    // Q B-fragments for both 16-col q-tiles
    bf16x8 bQa0 = ld8(Qp + (size_t)(q0 + lo) * DK_ + quad * 8);
    bf16x8 bQa1 = ld8(Qp + (size_t)(q0 + lo) * DK_ + 32 + quad * 8);
    bf16x8 bQb0 = ld8(Qp + (size_t)(q0 + 16 + lo) * DK_ + quad * 8);
    bf16x8 bQb1 = ld8(Qp + (size_t)(q0 + 16 + lo) * DK_ + 32 + quad * 8);

    f32x4 outA[4], outB[4];
#pragma unroll
    for (int t = 0; t < 4; t++) {
        outA[t] = (f32x4){0.f, 0.f, 0.f, 0.f};
        outB[t] = (f32x4){0.f, 0.f, 0.f, 0.f};
    }
    float lsumA = 0.f, lsumB = 0.f;

    const int nfull = qb;                        // iters 0..qb; last is the fringe
    const int srcl  = (quad & 1) * 32 + lo;
    const bool loT  = (quad < 2);

    // prefetch K A-frags for it=0
    const bf16* kp0 = Kp + (size_t)lo * DK_ + quad * 8;
    bf16x8 a00 = ld8(kp0), a01 = ld8(kp0 + 32);
    bf16x8 a10 = ld8(kp0 + 16 * DK_), a11 = ld8(kp0 + 16 * DK_ + 32);

    for (int it = 0; it <= nfull; ++it) {
        const int kv0 = it * 32;
        const bool masked = (it == nfull);

        // V loads issued early; consumed after exp/shuffle (~200 cyc of cover)
        bf16x8 aV[4];
#pragma unroll
        for (int t = 0; t < 4; t++)
            aV[t] = ld8(Vp + (size_t)(t * 16 + lo) * S_ + kv0 + quad * 8);

        f32x4 stA0 = (f32x4){0.f,0.f,0.f,0.f}, stA1 = (f32x4){0.f,0.f,0.f,0.f};
        f32x4 stB0 = (f32x4){0.f,0.f,0.f,0.f}, stB1 = (f32x4){0.f,0.f,0.f,0.f};
        stA0 = __builtin_amdgcn_mfma_f32_16x16x32_bf16(a00, bQa0, stA0, 0, 0, 0);
        stA0 = __builtin_amdgcn_mfma_f32_16x16x32_bf16(a01, bQa1, stA0, 0, 0, 0);
        stA1 = __builtin_amdgcn_mfma_f32_16x16x32_bf16(a10, bQa0, stA1, 0, 0, 0);
        stA1 = __builtin_amdgcn_mfma_f32_16x16x32_bf16(a11, bQa1, stA1, 0, 0, 0);
        stB0 = __builtin_amdgcn_mfma_f32_16x16x32_bf16(a00, bQb0, stB0, 0, 0, 0);
        stB0 = __builtin_amdgcn_mfma_f32_16x16x32_bf16(a01, bQb1, stB0, 0, 0, 0);
        stB1 = __builtin_amdgcn_mfma_f32_16x16x32_bf16(a10, bQb0, stB1, 0, 0, 0);
        stB1 = __builtin_amdgcn_mfma_f32_16x16x32_bf16(a11, bQb1, stB1, 0, 0, 0);

        // prefetch next iteration's K A-frags (clamped on last iter; values unused)
        {
            const int kvn = masked ? kv0 : kv0 + 32;
            const bf16* kn = Kp + (size_t)(kvn + lo) * DK_ + quad * 8;
            a00 = ld8(kn); a01 = ld8(kn + 32);
            a10 = ld8(kn + 16 * DK_); a11 = ld8(kn + 16 * DK_ + 32);
        }

        float pA0[4], pA1[4], pB0[4], pB1[4];
#pragma unroll
        for (int r = 0; r < 4; r++) {
            float eA0 = exp2f(stA0[r]);
            float eA1 = exp2f(stA1[r]);
            float eB0 = exp2f(stB0[r]);
            float eB1 = exp2f(stB1[r]);
            if (masked) {
                bool c = (quad * 4 + r) <= lo;   // kv offset <= q offset (within tile)
                eA0 = c ? eA0 : 0.f;             // tileA vs kv sub0: diagonal
                eA1 = 0.f;                       // tileA vs kv sub1: fully masked
                eB1 = c ? eB1 : 0.f;             // tileB vs kv sub1: diagonal
            }                                    // tileB vs kv sub0: fully unmasked
            pA0[r] = eA0; pA1[r] = eA1; pB0[r] = eB0; pB1[r] = eB1;
            lsumA += eA0 + eA1;
            lsumB += eB0 + eB1;
        }

        bf16x8 bPA = transpose_p(pA0, pA1, srcl, loT);
        bf16x8 bPB = transpose_p(pB0, pB1, srcl, loT);

#pragma unroll
        for (int t = 0; t < 4; t++) {
            outA[t] = __builtin_amdgcn_mfma_f32_16x16x32_bf16(aV[t], bPA, outA[t], 0, 0, 0);
            outB[t] = __builtin_amdgcn_mfma_f32_16x16x32_bf16(aV[t], bPB, outB[t], 0, 0, 0);
        }
    }

    lsumA += __shfl_xor(lsumA, 16, 64);
    lsumA += __shfl_xor(lsumA, 32, 64);
    lsumB += __shfl_xor(lsumB, 16, 64);
    lsumB += __shfl_xor(lsumB, 32, 64);
    const float rlA = 1.f / lsumA;
    const float rlB = 1.f / lsumB;

    const int b = bh >> 4, h = bh & 15;
    bf16* XpA = X + (size_t)(b * S_ + q0 + lo) * D_ + h * 64;
    bf16* XpB = XpA + (size_t)16 * D_;
#pragma unroll
    for (int t = 0; t < 4; t++) {
        uint32_t* dA = (uint32_t*)(XpA + t * 16 + quad * 4);
        dA[0] = pk2(outA[t][0] * rlA, outA[t][1] * rlA);
        dA[1] = pk2(outA[t][2] * rlA, outA[t][3] * rlA);
        uint32_t* dB = (uint32_t*)(XpB + t * 16 + quad * 4);
        dB[0] = pk2(outB[t][0] * rlB, outB[t][1] * rlB);
        dB[1] = pk2(outB[t][2] * rlB, outB[t][3] * rlB);
    }
}

extern "C" void kernel_launch(void* const* d_in, const int* in_sizes, int n_in,
                              void* d_out, int out_size, void* d_ws, size_t ws_size,
                              hipStream_t stream) {
    const float* q  = (const float*)d_in[0];
    const float* k  = (const float*)d_in[1];
    const float* v  = (const float*)d_in[2];
    const float* wq = (const float*)d_in[4];
    const float* wk = (const float*)d_in[5];
    const float* wv = (const float*)d_in[6];
    const float* wo = (const float*)d_in[7];

    const size_t elems = (size_t)B_ * S_ * D_;   // 8388608
    const size_t welems = (size_t)D_ * D_;       // 1048576
    // ws (bf16): Xb[elems] | Wb[welems] | Qw | Kw | Vw = 69.2 MB (proven fit)
    bf16* Xb = (bf16*)d_ws;
    bf16* Wb = Xb + elems;
    bf16* Qw = Wb + welems;
    bf16* Kw = Qw + elems;
    bf16* Vw = Kw + elems;

    const int n4a = (int)(elems / 4);
    const int n4w = (int)(welems / 4);
    const int cg  = (n4a + n4w) / 256;
    dim3 gg(D_ / 128, (B_ * S_) / 128);   // (8, 64)

    hipLaunchKernelGGL(cvt2, dim3(cg), dim3(256), 0, stream,
                       (const float4*)q, (bf16x4*)Xb, n4a, (const float4*)wq, (bf16x4*)Wb, n4w);
    hipLaunchKernelGGL(gemm_bt, gg, dim3(256), 0, stream, Xb, Wb, (void*)Qw, 3);
    hipLaunchKernelGGL(cvt2, dim3(cg), dim3(256), 0, stream,
                       (const float4*)k, (bf16x4*)Xb, n4a, (const float4*)wk, (bf16x4*)Wb, n4w);
    hipLaunchKernelGGL(gemm_bt, gg, dim3(256), 0, stream, Xb, Wb, (void*)Kw, 0);
    hipLaunchKernelGGL(cvt2, dim3(cg), dim3(256), 0, stream,
                       (const float4*)v, (bf16x4*)Xb, n4a, (const float4*)wv, (bf16x4*)Wb, n4w);
    hipLaunchKernelGGL(gemm_bt, gg, dim3(256), 0, stream, Xb, Wb, (void*)Vw, 1);

    hipLaunchKernelGGL(attn, dim3((S_ / 32) * B_ * H_), dim3(64), 0, stream, Qw, Kw, Vw, Xb);

    hipLaunchKernelGGL(cvt2, dim3(n4w / 256), dim3(256), 0, stream,
                       (const float4*)nullptr, (bf16x4*)nullptr, 0,
                       (const float4*)wo, (bf16x4*)Wb, n4w);
    hipLaunchKernelGGL(gemm_bt, gg, dim3(256), 0, stream, Xb, Wb, d_out, 2);
}

// Round 6
// 432.740 us; speedup vs baseline: 1.4733x; 1.0017x over previous
//
#include <hip/hip_runtime.h>
#include <hip/hip_bf16.h>
#include <stdint.h>

#define B_ 4
#define S_ 2048
#define D_ 1024
#define H_ 16
#define DK_ 64

typedef __hip_bfloat16 bf16;
typedef __attribute__((ext_vector_type(8))) __bf16 bf16x8;
typedef __attribute__((ext_vector_type(4))) __bf16 bf16x4;
typedef __attribute__((ext_vector_type(4))) float f32x4;
typedef __attribute__((ext_vector_type(4))) uint32_t u32x4;

// scale 1/sqrt(DK) folded with log2(e): Q pre-scaled so p = exp2(S^T) directly
#define QSCALE 0.18033688011112042f   // 0.125 * 1.4426950408889634

__device__ __forceinline__ void async_copy16(const void* g, void* l) {
    __builtin_amdgcn_global_load_lds((const __attribute__((address_space(1))) void*)g,
                                     (__attribute__((address_space(3))) void*)l,
                                     16, 0, 0);
}

__device__ __forceinline__ bf16x8 ld8(const bf16* p) {
    return *(const bf16x8*)p;
}

__device__ __forceinline__ uint32_t pk2(float a, float b) {
    union { __bf16 h; uint16_t u; } x, y;
    x.h = (__bf16)a; y.h = (__bf16)b;
    return (uint32_t)x.u | ((uint32_t)y.u << 16);
}

__device__ __forceinline__ bf16x8 cvt8(float4 u0, float4 u1) {
    return (bf16x8){(__bf16)u0.x, (__bf16)u0.y, (__bf16)u0.z, (__bf16)u0.w,
                    (__bf16)u1.x, (__bf16)u1.y, (__bf16)u1.z, (__bf16)u1.w};
}

// C-layout 16x32 P-tile (two 16x16 subtiles p0,p1) -> B-fragment of P^T (k=32, n=16)
__device__ __forceinline__ bf16x8 transpose_p(const float* p0, const float* p1,
                                              int srcl, bool loT) {
    uint32_t x0 = pk2(p0[0], p0[1]), x1 = pk2(p0[2], p0[3]);
    uint32_t y0 = pk2(p1[0], p1[1]), y1 = pk2(p1[2], p1[3]);
    u32x4 dw;
#pragma unroll
    for (int i = 0; i < 4; i++) {
        int sl = srcl + (i >> 1) * 16;
        uint32_t vA = (uint32_t)__shfl((int)((i & 1) ? x1 : x0), sl, 64);
        uint32_t vB = (uint32_t)__shfl((int)((i & 1) ? y1 : y0), sl, 64);
        dw[i] = loT ? vA : vB;
    }
    return __builtin_bit_cast(bf16x8, dw);
}

// convert the 4 weight matrices f32->bf16 in one launch (4 x 262144 float4)
__global__ __launch_bounds__(256) void cvtw(const float4* __restrict__ s0,
                                            const float4* __restrict__ s1,
                                            const float4* __restrict__ s2,
                                            const float4* __restrict__ s3,
                                            bf16x4* __restrict__ d0,
                                            bf16x4* __restrict__ d1,
                                            bf16x4* __restrict__ d2,
                                            bf16x4* __restrict__ d3) {
    int i = blockIdx.x * 256 + threadIdx.x;
    int seg = i >> 18;            // 262144 float4 per matrix
    int j   = i & 262143;
    const float4* s = seg == 0 ? s0 : seg == 1 ? s1 : seg == 2 ? s2 : s3;
    bf16x4*       d = seg == 0 ? d0 : seg == 1 ? d1 : seg == 2 ? d2 : d3;
    float4 f = s[j];
    d[j] = (bf16x4){(__bf16)f.x, (__bf16)f.y, (__bf16)f.z, (__bf16)f.w};
}

// Fused Q/K/V projection: one launch, gridDim.z selects {q,k,v}.
// A is raw float32 [8192 x 1024]; converted to bf16 in-register during staging.
// W bf16 [1024 x 1024] K-major via async global_load_lds.
// z=0: Q (scaled, layout [bh][s][dk]); z=1: K (same layout); z=2: V (transposed [bh][dk][s]).
__global__ __launch_bounds__(256) void gemm_qkv(const float* __restrict__ Aq,
                                                const float* __restrict__ Ak,
                                                const float* __restrict__ Av,
                                                const bf16* __restrict__ Wqb,
                                                const bf16* __restrict__ Wkb,
                                                const bf16* __restrict__ Wvb,
                                                bf16* __restrict__ Oq,
                                                bf16* __restrict__ Ok,
                                                bf16* __restrict__ Ov) {
    __shared__ bf16 lA[128 * 32];
    __shared__ bf16 lW[128 * 32];
    const int z = blockIdx.z;
    const float* A = z == 0 ? Aq : z == 1 ? Ak : Av;
    const bf16*  W = z == 0 ? Wqb : z == 1 ? Wkb : Wvb;
    bf16*      out = z == 0 ? Oq : z == 1 ? Ok : Ov;

    const int tid  = threadIdx.x;
    const int lane = tid & 63;
    const int quad = lane >> 4;
    const int lo   = lane & 15;
    const int wave = tid >> 6;
    const int wm   = (wave >> 1) * 64;
    const int wn   = (wave & 1) * 64;
    const int n0   = blockIdx.x * 128;
    const int m0   = blockIdx.y * 128;
    const int K    = 1024;

    f32x4 acc[4][4];
#pragma unroll
    for (int i = 0; i < 4; i++)
#pragma unroll
        for (int j = 0; j < 4; j++) acc[i][j] = (f32x4){0.f, 0.f, 0.f, 0.f};

    const int sr = tid >> 2;
    const int sc = (tid & 3) * 8;

    for (int k0 = 0; k0 < K; k0 += 32) {
        // W: async 16B direct-to-LDS
        async_copy16(W + (size_t)(n0 + sr) * K + k0 + sc,       lW + sr * 32 + sc);
        async_copy16(W + (size_t)(n0 + 64 + sr) * K + k0 + sc,  lW + (64 + sr) * 32 + sc);
        // A: f32 load -> cvt -> 16B LDS write (fused conversion)
        const float* a0 = A + (size_t)(m0 + sr) * K + k0 + sc;
        const float* a1 = A + (size_t)(m0 + 64 + sr) * K + k0 + sc;
        float4 u0 = *(const float4*)a0;
        float4 u1 = *(const float4*)(a0 + 4);
        float4 u2 = *(const float4*)a1;
        float4 u3 = *(const float4*)(a1 + 4);
        *(bf16x8*)(lA + sr * 32 + sc)        = cvt8(u0, u1);
        *(bf16x8*)(lA + (64 + sr) * 32 + sc) = cvt8(u2, u3);
        __syncthreads();

        bf16x8 af[4], bfr[4];
#pragma unroll
        for (int i = 0; i < 4; i++)
            af[i] = ld8(lA + (wm + i * 16 + lo) * 32 + quad * 8);
#pragma unroll
        for (int j = 0; j < 4; j++)
            bfr[j] = ld8(lW + (wn + j * 16 + lo) * 32 + quad * 8);
#pragma unroll
        for (int i = 0; i < 4; i++)
#pragma unroll
            for (int j = 0; j < 4; j++)
                acc[i][j] = __builtin_amdgcn_mfma_f32_16x16x32_bf16(af[i], bfr[j], acc[i][j], 0, 0, 0);
        __syncthreads();
    }

#pragma unroll
    for (int i = 0; i < 4; i++)
#pragma unroll
        for (int j = 0; j < 4; j++)
#pragma unroll
            for (int r = 0; r < 4; r++) {
                int m = m0 + wm + i * 16 + quad * 4 + r;
                int n = n0 + wn + j * 16 + lo;
                float val = acc[i][j][r];
                int b = m >> 11, s = m & (S_ - 1);
                int h = n >> 6, dk = n & 63;
                if (z == 0) {
                    out[((size_t)(b * H_ + h) * S_ + s) * DK_ + dk] =
                        __float2bfloat16(val * QSCALE);
                } else if (z == 1) {
                    out[((size_t)(b * H_ + h) * S_ + s) * DK_ + dk] = __float2bfloat16(val);
                } else {
                    out[((size_t)(b * H_ + h) * DK_ + dk) * S_ + s] = __float2bfloat16(val);
                }
            }
}

// Final projection: A bf16 (attn output X), W bf16, out float32 [8192 x 1024]
__global__ __launch_bounds__(256) void gemm_out(const bf16* __restrict__ A,
                                                const bf16* __restrict__ W,
                                                float* __restrict__ out) {
    __shared__ bf16 lA[128 * 32];
    __shared__ bf16 lW[128 * 32];
    const int tid  = threadIdx.x;
    const int lane = tid & 63;
    const int quad = lane >> 4;
    const int lo   = lane & 15;
    const int wave = tid >> 6;
    const int wm   = (wave >> 1) * 64;
    const int wn   = (wave & 1) * 64;
    const int n0   = blockIdx.x * 128;
    const int m0   = blockIdx.y * 128;
    const int K    = 1024;

    f32x4 acc[4][4];
#pragma unroll
    for (int i = 0; i < 4; i++)
#pragma unroll
        for (int j = 0; j < 4; j++) acc[i][j] = (f32x4){0.f, 0.f, 0.f, 0.f};

    const int sr = tid >> 2;
    const int sc = (tid & 3) * 8;

    for (int k0 = 0; k0 < K; k0 += 32) {
        async_copy16(A + (size_t)(m0 + sr) * K + k0 + sc,       lA + sr * 32 + sc);
        async_copy16(A + (size_t)(m0 + 64 + sr) * K + k0 + sc,  lA + (64 + sr) * 32 + sc);
        async_copy16(W + (size_t)(n0 + sr) * K + k0 + sc,       lW + sr * 32 + sc);
        async_copy16(W + (size_t)(n0 + 64 + sr) * K + k0 + sc,  lW + (64 + sr) * 32 + sc);
        __syncthreads();

        bf16x8 af[4], bfr[4];
#pragma unroll
        for (int i = 0; i < 4; i++)
            af[i] = ld8(lA + (wm + i * 16 + lo) * 32 + quad * 8);
#pragma unroll
        for (int j = 0; j < 4; j++)
            bfr[j] = ld8(lW + (wn + j * 16 + lo) * 32 + quad * 8);
#pragma unroll
        for (int i = 0; i < 4; i++)
#pragma unroll
            for (int j = 0; j < 4; j++)
                acc[i][j] = __builtin_amdgcn_mfma_f32_16x16x32_bf16(af[i], bfr[j], acc[i][j], 0, 0, 0);
        __syncthreads();
    }

#pragma unroll
    for (int i = 0; i < 4; i++)
#pragma unroll
        for (int j = 0; j < 4; j++)
#pragma unroll
            for (int r = 0; r < 4; r++) {
                int m = m0 + wm + i * 16 + quad * 4 + r;
                int n = n0 + wn + j * 16 + lo;
                out[(size_t)m * D_ + n] = acc[i][j][r];
            }
}

// Transposed flash attention, causal, no-max softmax. 1 wave / 32 q rows.
// (unchanged from round 5 — verified)
__global__ __launch_bounds__(64) void attn(const bf16* __restrict__ Q,
                                           const bf16* __restrict__ K,
                                           const bf16* __restrict__ Vt,
                                           bf16* __restrict__ X) {
    const int lane = threadIdx.x;
    const int quad = lane >> 4;
    const int lo   = lane & 15;
    const int idx  = blockIdx.x;
    const int bh   = idx & 63;          // XCD locality: one head stays on one XCD
    const int qb   = 63 - (idx >> 6);   // LPT: longest q-blocks dispatched first
    const int q0   = qb * 32;

    const bf16* Qp = Q  + (size_t)bh * S_ * DK_;
    const bf16* Kp = K  + (size_t)bh * S_ * DK_;
    const bf16* Vp = Vt + (size_t)bh * DK_ * S_;

    bf16x8 bQa0 = ld8(Qp + (size_t)(q0 + lo) * DK_ + quad * 8);
    bf16x8 bQa1 = ld8(Qp + (size_t)(q0 + lo) * DK_ + 32 + quad * 8);
    bf16x8 bQb0 = ld8(Qp + (size_t)(q0 + 16 + lo) * DK_ + quad * 8);
    bf16x8 bQb1 = ld8(Qp + (size_t)(q0 + 16 + lo) * DK_ + 32 + quad * 8);

    f32x4 outA[4], outB[4];
#pragma unroll
    for (int t = 0; t < 4; t++) {
        outA[t] = (f32x4){0.f, 0.f, 0.f, 0.f};
        outB[t] = (f32x4){0.f, 0.f, 0.f, 0.f};
    }
    float lsumA = 0.f, lsumB = 0.f;

    const int nfull = qb;
    const int srcl  = (quad & 1) * 32 + lo;
    const bool loT  = (quad < 2);

    const bf16* kp0 = Kp + (size_t)lo * DK_ + quad * 8;
    bf16x8 a00 = ld8(kp0), a01 = ld8(kp0 + 32);
    bf16x8 a10 = ld8(kp0 + 16 * DK_), a11 = ld8(kp0 + 16 * DK_ + 32);

    for (int it = 0; it <= nfull; ++it) {
        const int kv0 = it * 32;
        const bool masked = (it == nfull);

        bf16x8 aV[4];
#pragma unroll
        for (int t = 0; t < 4; t++)
            aV[t] = ld8(Vp + (size_t)(t * 16 + lo) * S_ + kv0 + quad * 8);

        f32x4 stA0 = (f32x4){0.f,0.f,0.f,0.f}, stA1 = (f32x4){0.f,0.f,0.f,0.f};
        f32x4 stB0 = (f32x4){0.f,0.f,0.f,0.f}, stB1 = (f32x4){0.f,0.f,0.f,0.f};
        stA0 = __builtin_amdgcn_mfma_f32_16x16x32_bf16(a00, bQa0, stA0, 0, 0, 0);
        stA0 = __builtin_amdgcn_mfma_f32_16x16x32_bf16(a01, bQa1, stA0, 0, 0, 0);
        stA1 = __builtin_amdgcn_mfma_f32_16x16x32_bf16(a10, bQa0, stA1, 0, 0, 0);
        stA1 = __builtin_amdgcn_mfma_f32_16x16x32_bf16(a11, bQa1, stA1, 0, 0, 0);
        stB0 = __builtin_amdgcn_mfma_f32_16x16x32_bf16(a00, bQb0, stB0, 0, 0, 0);
        stB0 = __builtin_amdgcn_mfma_f32_16x16x32_bf16(a01, bQb1, stB0, 0, 0, 0);
        stB1 = __builtin_amdgcn_mfma_f32_16x16x32_bf16(a10, bQb0, stB1, 0, 0, 0);
        stB1 = __builtin_amdgcn_mfma_f32_16x16x32_bf16(a11, bQb1, stB1, 0, 0, 0);

        {
            const int kvn = masked ? kv0 : kv0 + 32;
            const bf16* kn = Kp + (size_t)(kvn + lo) * DK_ + quad * 8;
            a00 = ld8(kn); a01 = ld8(kn + 32);
            a10 = ld8(kn + 16 * DK_); a11 = ld8(kn + 16 * DK_ + 32);
        }

        float pA0[4], pA1[4], pB0[4], pB1[4];
#pragma unroll
        for (int r = 0; r < 4; r++) {
            float eA0 = exp2f(stA0[r]);
            float eA1 = exp2f(stA1[r]);
            float eB0 = exp2f(stB0[r]);
            float eB1 = exp2f(stB1[r]);
            if (masked) {
                bool c = (quad * 4 + r) <= lo;
                eA0 = c ? eA0 : 0.f;
                eA1 = 0.f;
                eB1 = c ? eB1 : 0.f;
            }
            pA0[r] = eA0; pA1[r] = eA1; pB0[r] = eB0; pB1[r] = eB1;
            lsumA += eA0 + eA1;
            lsumB += eB0 + eB1;
        }

        bf16x8 bPA = transpose_p(pA0, pA1, srcl, loT);
        bf16x8 bPB = transpose_p(pB0, pB1, srcl, loT);

#pragma unroll
        for (int t = 0; t < 4; t++) {
            outA[t] = __builtin_amdgcn_mfma_f32_16x16x32_bf16(aV[t], bPA, outA[t], 0, 0, 0);
            outB[t] = __builtin_amdgcn_mfma_f32_16x16x32_bf16(aV[t], bPB, outB[t], 0, 0, 0);
        }
    }

    lsumA += __shfl_xor(lsumA, 16, 64);
    lsumA += __shfl_xor(lsumA, 32, 64);
    lsumB += __shfl_xor(lsumB, 16, 64);
    lsumB += __shfl_xor(lsumB, 32, 64);
    const float rlA = 1.f / lsumA;
    const float rlB = 1.f / lsumB;

    const int b = bh >> 4, h = bh & 15;
    bf16* XpA = X + (size_t)(b * S_ + q0 + lo) * D_ + h * 64;
    bf16* XpB = XpA + (size_t)16 * D_;
#pragma unroll
    for (int t = 0; t < 4; t++) {
        uint32_t* dA = (uint32_t*)(XpA + t * 16 + quad * 4);
        dA[0] = pk2(outA[t][0] * rlA, outA[t][1] * rlA);
        dA[1] = pk2(outA[t][2] * rlA, outA[t][3] * rlA);
        uint32_t* dB = (uint32_t*)(XpB + t * 16 + quad * 4);
        dB[0] = pk2(outB[t][0] * rlB, outB[t][1] * rlB);
        dB[1] = pk2(outB[t][2] * rlB, outB[t][3] * rlB);
    }
}

extern "C" void kernel_launch(void* const* d_in, const int* in_sizes, int n_in,
                              void* d_out, int out_size, void* d_ws, size_t ws_size,
                              hipStream_t stream) {
    const float* q  = (const float*)d_in[0];
    const float* k  = (const float*)d_in[1];
    const float* v  = (const float*)d_in[2];
    const float* wq = (const float*)d_in[4];
    const float* wk = (const float*)d_in[5];
    const float* wv = (const float*)d_in[6];
    const float* wo = (const float*)d_in[7];

    const size_t elems  = (size_t)B_ * S_ * D_;   // 8388608
    const size_t welems = (size_t)D_ * D_;        // 1048576
    // ws layout (bf16 elems), total 34603008 elems = 69.2 MB (size proven in r3-r5):
    //   [Wo: 1M][Wq: 1M][Wk: 1M][Wv: 1M ... X region spans Wq..Wv+pad: 8M][Qw][Kw][Vw]
    // X (attn output, 8M elems) starts at Wq and overwrites the three dead
    // projection weight buffers — safe: attn reads only Qw/Kw/Vw; Wo untouched.
    bf16* WoB = (bf16*)d_ws;            // elem 0
    bf16* WqB = WoB + welems;           // elem 1M
    bf16* WkB = WqB + welems;           // elem 2M
    bf16* WvB = WkB + welems;           // elem 3M
    bf16* Xb  = WqB;                    // elem 1M .. 1M+8M (aliases Wq/Wk/Wv by design)
    bf16* Qw  = WqB + elems;            // elem 1M+8M
    bf16* Kw  = Qw + elems;
    bf16* Vw  = Kw + elems;

    // 1. convert all four weight matrices (one launch)
    hipLaunchKernelGGL(cvtw, dim3(4 * (int)(welems / 4) / 256), dim3(256), 0, stream,
                       (const float4*)wq, (const float4*)wk, (const float4*)wv,
                       (const float4*)wo,
                       (bf16x4*)WqB, (bf16x4*)WkB, (bf16x4*)WvB, (bf16x4*)WoB);
    // 2. fused Q/K/V projection, one launch, f32 activations converted in-register
    hipLaunchKernelGGL(gemm_qkv, dim3(D_ / 128, (B_ * S_) / 128, 3), dim3(256), 0, stream,
                       q, k, v, WqB, WkB, WvB, Qw, Kw, Vw);
    // 3. attention
    hipLaunchKernelGGL(attn, dim3((S_ / 32) * B_ * H_), dim3(64), 0, stream, Qw, Kw, Vw, Xb);
    // 4. output projection -> d_out (f32)
    hipLaunchKernelGGL(gemm_out, dim3(D_ / 128, (B_ * S_) / 128), dim3(256), 0, stream,
                       Xb, WoB, (float*)d_out);
}